// Round 1
// baseline (135.304 us; speedup 1.0000x reference)
//
#include <hip/hip_runtime.h>
#include <cfloat>
#include <cstdint>

// Problem constants (match reference)
constexpr int B = 32, H = 24, L = 800, T = 200;
constexpr int ROWS = B * H * L;           // 614400
constexpr int F4_PER_ROW = T / 4;         // 50

// ws layout (bytes):
//   [0,192)                double diag[H]
//   [192,196)              int head
//   [256, 256+ROWS*4)      float rowmax[ROWS]
//   [256+ROWS*4, +ROWS*4)  int amax[ROWS]
// total ~4.9 MB

// ---------------------------------------------------------------------------
// Pass 1: one 16-lane group per row. Computes:
//   rowmax[row] = max over all t (unmasked)  -> for diagonal score
//   amax[row]   = first-occurrence argmax over t < ilen[b]
// float4 loads: 16B/lane, coalesced 256B per 16-lane group.
__global__ __launch_bounds__(256) void k_rowscan(const float* __restrict__ att,
                                                 const int* __restrict__ ilens,
                                                 float* __restrict__ rowmax,
                                                 int* __restrict__ amax) {
    const int tid = threadIdx.x;
    const int grp = tid >> 4;          // 0..15 (16 rows per block)
    const int j   = tid & 15;          // lane within group
    const int row = blockIdx.x * 16 + grp;   // grid sized exactly, 800%16==0 so block never crosses (b,h)
    const int b   = row / (H * L);
    const int ilen = ilens[b];

    const float4* p = reinterpret_cast<const float4*>(att + (size_t)row * T);

    float rmax = -FLT_MAX;
    float bv   = -FLT_MAX;
    int   bi   = 0x7fffffff;

    #pragma unroll
    for (int k = 0; k < 4; ++k) {
        const int f = j + 16 * k;      // float4 index within row
        if (f < F4_PER_ROW) {
            const float4 v = p[f];
            const int t0 = 4 * f;
            rmax = fmaxf(rmax, fmaxf(fmaxf(v.x, v.y), fmaxf(v.z, v.w)));
            const float vals[4] = {v.x, v.y, v.z, v.w};
            #pragma unroll
            for (int e = 0; e < 4; ++e) {
                const int t = t0 + e;
                if (t < ilen && (vals[e] > bv || (vals[e] == bv && t < bi))) {
                    bv = vals[e];
                    bi = t;
                }
            }
        }
    }

    // reduce within the 16-lane group (xor masks < 16 stay inside the group)
    #pragma unroll
    for (int off = 8; off >= 1; off >>= 1) {
        const float ov  = __shfl_xor(bv, off);
        const int   oi  = __shfl_xor(bi, off);
        const float orm = __shfl_xor(rmax, off);
        rmax = fmaxf(rmax, orm);
        if (ov > bv || (ov == bv && oi < bi)) { bv = ov; bi = oi; }
    }

    if (j == 0) {
        rowmax[row] = rmax;
        amax[row]   = bi;
    }
}

// ---------------------------------------------------------------------------
// Pass 2: deterministic per-head sum of rowmax in double. One block per head.
__global__ __launch_bounds__(256) void k_diag(const float* __restrict__ rowmax,
                                              double* __restrict__ diag) {
    const int h = blockIdx.x;
    double s = 0.0;
    for (int c = threadIdx.x; c < B * L; c += 256) {
        const int b = c / L;
        const int l = c - b * L;
        s += (double)rowmax[((size_t)b * H + h) * L + l];
    }
    __shared__ double sh[256];
    sh[threadIdx.x] = s;
    __syncthreads();
    #pragma unroll
    for (int off = 128; off >= 1; off >>= 1) {
        if (threadIdx.x < off) sh[threadIdx.x] += sh[threadIdx.x + off];
        __syncthreads();
    }
    if (threadIdx.x == 0) diag[h] = sh[0];
}

// ---------------------------------------------------------------------------
// Pass 3: argmax over H diag scores, first-index tie-break. Trivial serial.
__global__ void k_head(const double* __restrict__ diag, int* __restrict__ head) {
    if (threadIdx.x == 0 && blockIdx.x == 0) {
        double best = diag[0];
        int bh = 0;
        for (int h = 1; h < H; ++h) {
            if (diag[h] > best) { best = diag[h]; bh = h; }
        }
        *head = bh;
    }
}

// ---------------------------------------------------------------------------
// Pass 4: per-batch LDS histogram of amax over l < olen[b]. One block per b.
// amax values are always < ilen[b] <= T, so bins beyond ilen stay zero, matching
// the reference's zero-padding. Writes ALL B*T outputs (d_out is poisoned).
__global__ __launch_bounds__(256) void k_hist(const int* __restrict__ amax,
                                              const int* __restrict__ olens,
                                              const int* __restrict__ headp,
                                              int* __restrict__ out) {
    const int b = blockIdx.x;
    const int head = *headp;
    const int olen = olens[b];

    __shared__ int hist[T];
    for (int t = threadIdx.x; t < T; t += 256) hist[t] = 0;
    __syncthreads();

    const int* arow = amax + ((size_t)b * H + head) * L;
    for (int l = threadIdx.x; l < olen; l += 256) {
        atomicAdd(&hist[arow[l]], 1);
    }
    __syncthreads();

    for (int t = threadIdx.x; t < T; t += 256) {
        out[b * T + t] = hist[t];
    }
}

// ---------------------------------------------------------------------------
extern "C" void kernel_launch(void* const* d_in, const int* in_sizes, int n_in,
                              void* d_out, int out_size, void* d_ws, size_t ws_size,
                              hipStream_t stream) {
    const float* att   = (const float*)d_in[0];
    const int*   ilens = (const int*)d_in[1];
    const int*   olens = (const int*)d_in[2];
    int* out = (int*)d_out;   // reference output dtype is int32

    char* ws = (char*)d_ws;
    double* diag   = (double*)(ws);
    int*    head   = (int*)(ws + 192);
    float*  rowmax = (float*)(ws + 256);
    int*    amax   = (int*)(ws + 256 + (size_t)ROWS * 4);

    // Pass 1: stream the 491.5 MB tensor once
    k_rowscan<<<ROWS / 16, 256, 0, stream>>>(att, ilens, rowmax, amax);
    // Pass 2: per-head deterministic double sum
    k_diag<<<H, 256, 0, stream>>>(rowmax, diag);
    // Pass 3: pick head
    k_head<<<1, 64, 0, stream>>>(diag, head);
    // Pass 4: histogram -> durations
    k_hist<<<B, 256, 0, stream>>>(amax, olens, head, out);
}

// Round 2
// 106.606 us; speedup vs baseline: 1.2692x; 1.2692x over previous
//
#include <hip/hip_runtime.h>
#include <cfloat>
#include <cstdint>

// Problem constants (match reference)
constexpr int B = 32, H = 24, L = 800, T = 200;
constexpr int ROWS = B * H * L;      // 614400
constexpr int TASKS = ROWS / 16;     // 38400 (16 rows per block-iteration)
constexpr int GRID = 1920;           // persistent blocks
constexpr int TPB_TASKS = TASKS / GRID;  // 20 contiguous tasks per block

typedef float v4f __attribute__((ext_vector_type(4)));

__device__ inline v4f nt_load(const v4f* p) {
    return __builtin_nontemporal_load(p);
}

// ws layout (bytes):
//   [0,192)              double diag[H]      (zeroed via hipMemsetAsync each call)
//   [256, 256+ROWS)      uint8 amax[ROWS]    (argmax < 200, fits a byte)

__device__ inline void upd(float v, int t, int ilen,
                           float& rmax, float& bv, int& bi) {
    rmax = fmaxf(rmax, v);
    if (t < ilen && (v > bv || (v == bv && t < bi))) { bv = v; bi = t; }
}

__device__ inline void upd4(const v4f v, int t0, int ilen,
                            float& rmax, float& bv, int& bi) {
    upd(v.x, t0 + 0, ilen, rmax, bv, bi);
    upd(v.y, t0 + 1, ilen, rmax, bv, bi);
    upd(v.z, t0 + 2, ilen, rmax, bv, bi);
    upd(v.w, t0 + 3, ilen, rmax, bv, bi);
}

// ---------------------------------------------------------------------------
// Persistent pass over the 491.5 MB tensor. Per 16-lane group: one row's
// unmasked max (-> diag score, fused) + masked first-occurrence argmax.
// Non-temporal float4 loads; 20 contiguous tasks per block.
__global__ __launch_bounds__(256) void k_rowscan(const float* __restrict__ att,
                                                 const int* __restrict__ ilens,
                                                 uint8_t* __restrict__ amax,
                                                 double* __restrict__ diag) {
    const int tid = threadIdx.x;
    const int grp = tid >> 4;        // 16 groups per block
    const int j = tid & 15;          // lane within group
    const int wlane = tid & 63;
    const int wv = tid >> 6;         // wave id (0..3)

    // per-wave (lane0) diag accumulation; block spans 320 rows < L=800 so at
    // most 2 distinct heads appear
    double acc0 = 0.0, acc1 = 0.0;
    int h0 = -1, h1 = -1;

    const int task0 = blockIdx.x * TPB_TASKS;

    #pragma unroll 2
    for (int it = 0; it < TPB_TASKS; ++it) {
        const int task = task0 + it;
        const int row = task * 16 + grp;
        const int b = row / (H * L);
        const int ilen = ilens[b];
        const v4f* p = reinterpret_cast<const v4f*>(att + (size_t)row * T);

        // 50 float4s per row: j, j+16, j+32 cover 0..47; lanes 0,1 take 48,49
        const v4f v0 = nt_load(p + j);
        const v4f v1 = nt_load(p + j + 16);
        const v4f v2 = nt_load(p + j + 32);

        float rmax = -FLT_MAX, bv = -FLT_MAX;
        int bi = 0x7fffffff;
        upd4(v0, 4 * j, ilen, rmax, bv, bi);
        upd4(v1, 4 * j + 64, ilen, rmax, bv, bi);
        upd4(v2, 4 * j + 128, ilen, rmax, bv, bi);
        if (j < 2) {
            const v4f v3 = nt_load(p + 48 + j);
            upd4(v3, 192 + 4 * j, ilen, rmax, bv, bi);
        }

        // reduce within the 16-lane group
        #pragma unroll
        for (int off = 8; off >= 1; off >>= 1) {
            const float ov = __shfl_xor(bv, off);
            const int oi = __shfl_xor(bi, off);
            const float orm = __shfl_xor(rmax, off);
            rmax = fmaxf(rmax, orm);
            if (ov > bv || (ov == bv && oi < bi)) { bv = ov; bi = oi; }
        }

        if (j == 0) amax[row] = (uint8_t)bi;

        // deterministic per-wave sum of the 4 group maxima (4 consecutive rows,
        // always same h since 800 % 4 == 0)
        const float rA = __shfl(rmax, 0);
        const float rB = __shfl(rmax, 16);
        const float rC = __shfl(rmax, 32);
        const float rD = __shfl(rmax, 48);
        if (wlane == 0) {
            const double s4 = ((double)rA + (double)rB) + ((double)rC + (double)rD);
            const int h = (row / L) % H;
            if (h == h0) acc0 += s4;
            else if (h == h1) acc1 += s4;
            else if (h0 < 0) { h0 = h; acc0 = s4; }
            else { h1 = h; acc1 = s4; }
        }
    }

    // merge the 4 waves' (h, acc) pairs in LDS; <=2 atomics per block
    __shared__ double s_acc[8];
    __shared__ int s_h[8];
    if (wlane == 0) {
        s_h[wv * 2] = h0;     s_acc[wv * 2] = acc0;
        s_h[wv * 2 + 1] = h1; s_acc[wv * 2 + 1] = acc1;
    }
    __syncthreads();
    if (tid == 0) {
        double a0 = 0.0, a1 = 0.0;
        int H0 = -1, H1 = -1;
        for (int i = 0; i < 8; ++i) {
            const int hh = s_h[i];
            if (hh < 0) continue;
            const double vv = s_acc[i];
            if (hh == H0) a0 += vv;
            else if (hh == H1) a1 += vv;
            else if (H0 < 0) { H0 = hh; a0 = vv; }
            else { H1 = hh; a1 = vv; }
        }
        if (H0 >= 0) atomicAdd(&diag[H0], a0);
        if (H1 >= 0) atomicAdd(&diag[H1], a1);
    }
}

// ---------------------------------------------------------------------------
// Head selection (serial over 24 doubles) + per-batch LDS histogram.
__global__ __launch_bounds__(256) void k_final(const uint8_t* __restrict__ amax,
                                               const int* __restrict__ olens,
                                               const double* __restrict__ diag,
                                               int* __restrict__ out) {
    __shared__ int s_head;
    __shared__ int hist[T];
    const int b = blockIdx.x;

    if (threadIdx.x == 0) {
        double best = diag[0];
        int bh = 0;
        for (int h = 1; h < H; ++h)
            if (diag[h] > best) { best = diag[h]; bh = h; }
        s_head = bh;
    }
    for (int t = threadIdx.x; t < T; t += 256) hist[t] = 0;
    __syncthreads();

    const int head = s_head;
    const int olen = olens[b];
    const uint8_t* arow = amax + ((size_t)b * H + head) * L;
    for (int l = threadIdx.x; l < olen; l += 256)
        atomicAdd(&hist[arow[l]], 1);
    __syncthreads();

    for (int t = threadIdx.x; t < T; t += 256)
        out[b * T + t] = hist[t];
}

// ---------------------------------------------------------------------------
extern "C" void kernel_launch(void* const* d_in, const int* in_sizes, int n_in,
                              void* d_out, int out_size, void* d_ws, size_t ws_size,
                              hipStream_t stream) {
    const float* att = (const float*)d_in[0];
    const int* ilens = (const int*)d_in[1];
    const int* olens = (const int*)d_in[2];
    int* out = (int*)d_out;

    char* ws = (char*)d_ws;
    double* diag = (double*)(ws);
    uint8_t* amax = (uint8_t*)(ws + 256);

    // diag accumulates via atomics -> must be zeroed every call
    hipMemsetAsync(diag, 0, H * sizeof(double), stream);

    k_rowscan<<<GRID, 256, 0, stream>>>(att, ilens, amax, diag);
    k_final<<<B, 256, 0, stream>>>(amax, olens, diag, out);
}

// Round 3
// 84.767 us; speedup vs baseline: 1.5962x; 1.2576x over previous
//
#include <hip/hip_runtime.h>
#include <cfloat>
#include <cstdint>

// Problem constants (match reference)
constexpr int B = 32, H = 24, L = 800, T = 200;
constexpr int ROWS = B * H * L;      // 614400
constexpr int GRID = 768;            // 3 blocks/CU exactly; 800 rows per block
constexpr int TPB = 50;              // tasks per block (16 rows per task)
constexpr int F4_ROW = T / 4;        // 50 float4 per row

typedef float v4f __attribute__((ext_vector_type(4)));

__device__ inline v4f ntl(const v4f* p) { return __builtin_nontemporal_load(p); }

// Each block covers rows [bid*800, bid*800+800) -> exactly one (b, h):
//   b = bid / 24, h = bid % 24. ilen is block-uniform.
// ws layout: double partial[768] at offset 0; uint8 amax[ROWS] at offset 8192.

__device__ inline void upd(float v, int t, int ilen,
                           float& rmax, float& bv, int& bi) {
    rmax = fmaxf(rmax, v);
    // values are uniform [0,1) -> -1.0f is a safe "-inf" sentinel; every lane's
    // first float4 is at t<64<=ilen so bv ends >=0 and sentinels never win.
    const float vm = (t < ilen) ? v : -1.0f;
    if (vm > bv) { bv = vm; bi = t; }   // strict '>' + increasing t = first occurrence
}

__device__ inline void upd4(const v4f v, int t0, int ilen,
                            float& rmax, float& bv, int& bi) {
    upd(v.x, t0 + 0, ilen, rmax, bv, bi);
    upd(v.y, t0 + 1, ilen, rmax, bv, bi);
    upd(v.z, t0 + 2, ilen, rmax, bv, bi);
    upd(v.w, t0 + 3, ilen, rmax, bv, bi);
}

__global__ __launch_bounds__(256) void k_rowscan(const float* __restrict__ att,
                                                 const int* __restrict__ ilens,
                                                 uint8_t* __restrict__ amax,
                                                 double* __restrict__ partial) {
    const int tid = threadIdx.x;
    const int grp = tid >> 4;          // 16 groups (rows) per task
    const int j   = tid & 15;          // lane within group
    const int bid = blockIdx.x;
    const int b   = bid / H;           // block-uniform batch
    const int ilen = ilens[b];         // scalar

    const int row0 = bid * 800 + grp;
    const v4f* p = (const v4f*)att + (size_t)row0 * F4_ROW;

    double acc = 0.0;                  // group leaders (j==0) only

    // prefetch task 0
    v4f c0 = ntl(p + j), c1 = ntl(p + j + 16), c2 = ntl(p + j + 32), c3{};
    if (j < 2) c3 = ntl(p + 48 + j);

    #pragma unroll 2
    for (int it = 0; it < TPB; ++it) {
        const v4f* pn = p + 16 * F4_ROW;
        v4f n0{}, n1{}, n2{}, n3{};
        if (it + 1 < TPB) {            // prefetch next task
            n0 = ntl(pn + j); n1 = ntl(pn + j + 16); n2 = ntl(pn + j + 32);
            if (j < 2) n3 = ntl(pn + 48 + j);
        }

        float rmax = -FLT_MAX, bv = -FLT_MAX;
        int bi = 0;
        upd4(c0, 4 * j,       ilen, rmax, bv, bi);
        upd4(c1, 4 * j + 64,  ilen, rmax, bv, bi);
        upd4(c2, 4 * j + 128, ilen, rmax, bv, bi);
        if (j < 2) upd4(c3, 192 + 4 * j, ilen, rmax, bv, bi);

        // reduce within the 16-lane group
        #pragma unroll
        for (int off = 8; off >= 1; off >>= 1) {
            const float ov = __shfl_xor(bv, off);
            const int   oi = __shfl_xor(bi, off);
            rmax = fmaxf(rmax, __shfl_xor(rmax, off));
            if (ov > bv || (ov == bv && oi < bi)) { bv = ov; bi = oi; }
        }

        if (j == 0) {
            amax[row0 + it * 16] = (uint8_t)bi;  // 4 consecutive bytes per wave
            acc += (double)rmax;
        }

        c0 = n0; c1 = n1; c2 = n2; c3 = n3;
        p = pn;
    }

    // block reduce: 16 group-leader accs, fixed order -> deterministic
    __shared__ double sh[16];
    if (j == 0) sh[grp] = acc;
    __syncthreads();
    if (tid == 0) {
        double s = 0.0;
        #pragma unroll
        for (int i = 0; i < 16; ++i) s += sh[i];
        partial[bid] = s;
    }
}

// ---------------------------------------------------------------------------
// Head selection (fixed-tree reduce over 768 partials, deterministic) +
// per-batch LDS histogram. One block per batch element.
__global__ __launch_bounds__(256) void k_final(const uint8_t* __restrict__ amax,
                                               const int* __restrict__ olens,
                                               const double* __restrict__ partial,
                                               int* __restrict__ out) {
    __shared__ double shd[H];
    __shared__ int s_head;
    __shared__ int hist[T];
    const int tid = threadIdx.x;
    const int b = blockIdx.x;

    if (tid < 192) {                   // 8 threads per head
        const int h = tid >> 3, k = tid & 7;
        double s = 0.0;
        #pragma unroll
        for (int m = 0; m < 4; ++m)
            s += partial[(size_t)(k * 4 + m) * H + h];   // partial[bb*24 + h]
        s += __shfl_xor(s, 1);
        s += __shfl_xor(s, 2);
        s += __shfl_xor(s, 4);
        if (k == 0) shd[h] = s;
    }
    for (int t = tid; t < T; t += 256) hist[t] = 0;
    __syncthreads();

    if (tid == 0) {
        double best = shd[0]; int bh = 0;
        for (int h = 1; h < H; ++h)
            if (shd[h] > best) { best = shd[h]; bh = h; }
        s_head = bh;
    }
    __syncthreads();

    const int head = s_head;
    const int olen = olens[b];
    const uint8_t* arow = amax + ((size_t)b * H + head) * L;
    for (int l = tid; l < olen; l += 256)
        atomicAdd(&hist[arow[l]], 1);
    __syncthreads();

    for (int t = tid; t < T; t += 256)
        out[b * T + t] = hist[t];
}

// ---------------------------------------------------------------------------
extern "C" void kernel_launch(void* const* d_in, const int* in_sizes, int n_in,
                              void* d_out, int out_size, void* d_ws, size_t ws_size,
                              hipStream_t stream) {
    const float* att = (const float*)d_in[0];
    const int* ilens = (const int*)d_in[1];
    const int* olens = (const int*)d_in[2];
    int* out = (int*)d_out;

    char* ws = (char*)d_ws;
    double* partial = (double*)(ws);            // 768 * 8 = 6144 B
    uint8_t* amax   = (uint8_t*)(ws + 8192);    // 614400 B

    // every partial/amax slot is written unconditionally -> no memset needed
    k_rowscan<<<GRID, 256, 0, stream>>>(att, ilens, amax, partial);
    k_final<<<B, 256, 0, stream>>>(amax, olens, partial, out);
}